// Round 4
// baseline (790.980 us; speedup 1.0000x reference)
//
#include <hip/hip_runtime.h>
#include <stdint.h>

// CapsuleNet forward on MI355X — round 4.
// conv2: 256x256 tile, BK=32, 4-deep LDS pipeline, counted vmcnt(8) (T4),
//        XOR-swizzle both sides, 8 waves, grid 72nb x 8kz (kz->XCD L2 affinity).
// routing: gemm_s with FUSED softmax (bij -> s directly), gemm_gc split-K 4.
//
// ws layout (total ~134.8 MB):
//   hT  bf16 [512][20][20][256]   @0           104,857,600
//   A2  bf16 [256][20736]         @104,857,600  10,616,832
//   u   f32  [512][9216]          @115,474,432  18,874,368
//   bij f32  [1152][10]           @134,348,800      46,080
//   s   f32  [160][512]           @134,440,960     327,680
//  aliased over dead hT after conv2:
//   ub  bf16 [512][9216]          @0             9,437,184
//   ubT bf16 [9216][512]          @9,437,184     9,437,184
//   vb  bf16 [160][512]           @21,823,488      163,840

typedef unsigned short u16;
typedef unsigned int u32;
typedef short short8 __attribute__((ext_vector_type(8)));
typedef float f32x4 __attribute__((ext_vector_type(4)));

__device__ __forceinline__ u16 f2bf(float f) {
  u32 u = __float_as_uint(f);
  return (u16)((u + 0x7FFFu + ((u >> 16) & 1u)) >> 16);
}

__device__ __forceinline__ void gload_lds16(const void* g, void* l) {
  __builtin_amdgcn_global_load_lds(
      (const __attribute__((address_space(1))) void*)g,
      (__attribute__((address_space(3))) void*)l, 16, 0, 0);
}

// ---------------- conv1 + bias + ReLU -> hT[b][y][x][co] bf16 ----------------
__global__ __launch_bounds__(256) void conv1_kernel(
    const float* __restrict__ x, const float* __restrict__ w1,
    const float* __restrict__ b1, u16* __restrict__ hT) {
  int b = blockIdx.x;
  int co0 = blockIdx.y * 128;
  int t = threadIdx.x;
  if (t >= 200) return;
  int oh = t / 10, ow0 = (t % 10) * 2;
  const float* xb = x + (size_t)b * 784;
  float patch[9][10];
#pragma unroll
  for (int kh = 0; kh < 9; ++kh)
#pragma unroll
    for (int j = 0; j < 10; ++j) patch[kh][j] = xb[(oh + kh) * 28 + ow0 + j];
  u16* hb = hT + ((size_t)b * 400 + oh * 20 + ow0) * 256 + co0;
  for (int c8 = 0; c8 < 16; ++c8) {
    u16 o0[8], o1[8];
#pragma unroll
    for (int cc = 0; cc < 8; ++cc) {
      int co = co0 + c8 * 8 + cc;
      const float* wc = w1 + co * 81;  // block-uniform -> s_load
      float a0 = 0.f, a1 = 0.f;
#pragma unroll
      for (int kh = 0; kh < 9; ++kh)
#pragma unroll
        for (int kw = 0; kw < 9; ++kw) {
          float wv = wc[kh * 9 + kw];
          a0 = fmaf(wv, patch[kh][kw], a0);
          a1 = fmaf(wv, patch[kh][kw + 1], a1);
        }
      float bias = b1[co];
      o0[cc] = f2bf(fmaxf(a0 + bias, 0.f));
      o1[cc] = f2bf(fmaxf(a1 + bias, 0.f));
    }
    *(uint4*)(hb + c8 * 8) = *(uint4*)o0;
    *(uint4*)(hb + 256 + c8 * 8) = *(uint4*)o1;
  }
}

// ---------------- conv2 weights: [co][ci][t] -> bf16 [co][t*256+ci] ----------------
__global__ __launch_bounds__(256) void prep_w2_kernel(
    const float* __restrict__ w2, u16* __restrict__ A2) {
  int idx = blockIdx.x * 256 + threadIdx.x;  // 5,308,416
  int co = idx / 20736, k = idx - co * 20736;
  int t = k >> 8, ci = k & 255;
  A2[idx] = f2bf(w2[(size_t)(co * 256 + ci) * 81 + t]);
}

// ---------------- u := bias (pre-init for conv2 atomic accumulation) ----------------
__global__ __launch_bounds__(256) void init_u_kernel(
    const float* __restrict__ b2, float* __restrict__ u) {
  int i = blockIdx.x * 256 + threadIdx.x;  // 1,179,648 float4s
  int b = i / 2304, j0 = (i - b * 2304) * 4;
  float4 v;
  v.x = b2[j0 / 36]; v.y = b2[(j0 + 1) / 36];
  v.z = b2[(j0 + 2) / 36]; v.w = b2[(j0 + 3) / 36];
  *(float4*)(u + (size_t)b * 9216 + j0) = v;
}

// ---------------- conv2 implicit GEMM: 256x256 tile, BK=32, 4-deep pipeline ----------------
// M=256(co, full) N=18432(b*36+s) K=81taps*256ci. Grid 576 = 72 nb * 8 kz.
// bx = nb*8+kz -> kz pins to one XCD (A2 slice L2-resident).
// LDS: 4 bufs x (A 16KB | B 16KB) = 128 KB. Per step, per thread: 4 gload_lds16.
// Pipeline: wait vmcnt(8) -> s_barrier -> STAGE(s+3) -> compute(s).
__global__ __launch_bounds__(512) void conv2_kernel(
    const u16* __restrict__ hT, const u16* __restrict__ A2,
    float* __restrict__ u) {
  __shared__ __align__(16) u16 lds[4 * 16384];  // bytes: buf*32768 + [A:16384|B:16384]
  int bx = blockIdx.x;
  int nbk = bx >> 3, kz = bx & 7;
  int n0 = nbk * 256;
  int tb = (81 * kz) >> 3, te = (81 * (kz + 1)) >> 3;
  int NS = (te - tb) * 8;
  int tid = threadIdx.x;
  int lane = tid & 63, w = tid >> 6;
  int wr = w >> 2, wc = w & 3;
  int fr = lane & 15, fg = lane >> 4;

  // staging chunks: thread covers chunk CA0 and CA1 (chunk = row*4 + q, 8-elem units)
  int CA0 = w * 128 + lane, CA1 = CA0 + 64;
  int r0 = CA0 >> 2, r1 = CA1 >> 2;
  int q0 = ((CA0 & 3) ^ (r0 & 3)) << 3;  // source pre-swizzle (rule 21)
  int q1 = ((CA1 & 3) ^ (r1 & 3)) << 3;
  int Aoff0 = r0 * 20736 + q0;
  int Aoff1 = r1 * 20736 + q1;
  int Boff0, Boff1;
  {
    int n = n0 + r0; int b = n / 36, sp = n - b * 36, oh = sp / 6, ow = sp - oh * 6;
    Boff0 = (b * 400 + oh * 40 + ow * 2) * 256 + q0;
    n = n0 + r1; b = n / 36; sp = n - b * 36; oh = sp / 6; ow = sp - oh * 6;
    Boff1 = (b * 400 + oh * 40 + ow * 2) * 256 + q1;
  }

  auto STAGE = [&](int s) {
    int buf = s & 3;
    int t = tb + (s >> 3), sub = s & 7;
    int kh = t / 9, kw = t - kh * 9;
    int ao = t * 256 + sub * 32;
    int bo = (kh * 20 + kw) * 256 + sub * 32;
    char* base = (char*)lds + buf * 32768 + w * 2048;
    gload_lds16(A2 + Aoff0 + ao, base);
    gload_lds16(A2 + Aoff1 + ao, base + 1024);
    gload_lds16(hT + Boff0 + bo, base + 16384);
    gload_lds16(hT + Boff1 + bo, base + 17408);
  };

  // fragment read addresses (read-side swizzle matches source pre-swizzle)
  int coff = (fg ^ (fr & 3)) << 4;
  int abase[8], bbase[4];
#pragma unroll
  for (int m = 0; m < 8; ++m) abase[m] = (wr * 128 + m * 16 + fr) * 64 + coff;
#pragma unroll
  for (int n = 0; n < 4; ++n) bbase[n] = 16384 + (wc * 64 + n * 16 + fr) * 64 + coff;

  f32x4 acc[8][4] = {};

  STAGE(0); STAGE(1); STAGE(2);
  for (int s = 0; s < NS; ++s) {
    asm volatile("s_waitcnt vmcnt(8)" ::: "memory");  // step-s loads landed; 2 steps in flight
    __builtin_amdgcn_s_barrier();                     // all waves' loads visible; prev readers done
    asm volatile("" ::: "memory");
    if (s + 3 < NS) STAGE(s + 3);
    const char* bb = (const char*)lds + (s & 3) * 32768;
    short8 af[8], bv[4];
#pragma unroll
    for (int m = 0; m < 8; ++m) af[m] = *(const short8*)(bb + abase[m]);
#pragma unroll
    for (int n = 0; n < 4; ++n) bv[n] = *(const short8*)(bb + bbase[n]);
#pragma unroll
    for (int m = 0; m < 8; ++m)
#pragma unroll
      for (int n = 0; n < 4; ++n)
        acc[m][n] = __builtin_amdgcn_mfma_f32_16x16x32_bf16(af[m], bv[n],
                                                            acc[m][n], 0, 0, 0);
  }

  // epilogue: atomic accumulate into u[b][co*36+s]
#pragma unroll
  for (int nn = 0; nn < 4; ++nn) {
    int cn = n0 + wc * 64 + nn * 16 + fr;
    int ob = cn / 36;
    int os = cn - ob * 36;
    float* op = u + (size_t)ob * 9216 + os;
#pragma unroll
    for (int m = 0; m < 8; ++m) {
      int row0 = wr * 128 + m * 16 + fg * 4;
#pragma unroll
      for (int qq = 0; qq < 4; ++qq)
        atomicAdd(op + (row0 + qq) * 36, acc[m][nn][qq]);
    }
  }
}

// ---------------- squash u -> ub (b-major) + ubT (ri-major), bf16 ----------------
__global__ __launch_bounds__(256) void squash_kernel(
    const float* __restrict__ u, u16* __restrict__ ub, u16* __restrict__ ubT) {
  int idx = blockIdx.x * 256 + threadIdx.x;  // 589,824 = r*512 + b
  int r = idx >> 9, b = idx & 511;
  const float* up = u + (size_t)b * 9216 + r * 8;
  float4 a = *(const float4*)up;
  float4 c = *(const float4*)(up + 4);
  float sq = a.x * a.x + a.y * a.y + a.z * a.z + a.w * a.w +
             c.x * c.x + c.y * c.y + c.z * c.z + c.w * c.w;
  float f = sqrtf(sq) / (1.0f + sq);
  u16 o[8];
  o[0] = f2bf(a.x * f); o[1] = f2bf(a.y * f);
  o[2] = f2bf(a.z * f); o[3] = f2bf(a.w * f);
  o[4] = f2bf(c.x * f); o[5] = f2bf(c.y * f);
  o[6] = f2bf(c.z * f); o[7] = f2bf(c.w * f);
  *(uint4*)(ub + ((size_t)b * 1152 + r) * 8) = *(uint4*)o;
#pragma unroll
  for (int i = 0; i < 8; ++i) ubT[(size_t)(r * 8 + i) * 512 + b] = o[i];
}

// ---------------- gemm_s (softmax fused): s[160co][512b] += softmax(bij)*W @ ub^T ----------------
// grid 288 = 8 nb * 36 kz; K=256/block (4 BK-64 steps). A tile built on the fly.
__global__ __launch_bounds__(256) void gemm_s_kernel(
    const float* __restrict__ W, const float* __restrict__ bij,
    const u16* __restrict__ ub, float* __restrict__ s) {
  __shared__ __align__(16) u16 Asl[160 * 72];
  __shared__ __align__(16) u16 Bsl[64 * 72];
  __shared__ float smx[10], sinv[10];
  int nb = blockIdx.x & 7, kzi = blockIdx.x >> 3;
  int n0 = nb * 64, k0 = kzi * 256;
  int tid = threadIdx.x;
  int lane = tid & 63, wave = tid >> 6;
  int fr = lane & 15, fg = lane >> 4;

  // fused softmax normalizers: wave w handles classes w, w+4, w+8
  for (int c = wave; c < 10; c += 4) {
    float mx = -1e30f;
    for (int r = lane; r < 1152; r += 64) mx = fmaxf(mx, bij[r * 10 + c]);
#pragma unroll
    for (int d = 1; d < 64; d <<= 1) mx = fmaxf(mx, __shfl_xor(mx, d, 64));
    float sm = 0.f;
    for (int r = lane; r < 1152; r += 64) sm += expf(bij[r * 10 + c] - mx);
#pragma unroll
    for (int d = 1; d < 64; d <<= 1) sm += __shfl_xor(sm, d, 64);
    if (lane == 0) { smx[c] = mx; sinv[c] = 1.0f / sm; }
  }

  f32x4 acc[10] = {};
#pragma unroll
  for (int st = 0; st < 4; ++st) {
    int kb = k0 + st * 64;
    __syncthreads();
#pragma unroll
    for (int j = 0; j < 5; ++j) {  // A: 160 rows x 8 chunks, built from W * c_ij
      int c5 = tid + j * 256;
      int row = c5 >> 3, qq = c5 & 7;
      int cls = row >> 4, o = row & 15;
      int r = (kb + qq * 8) >> 3;
      const float* wp = W + (size_t)r * 1280 + cls * 128 + o * 8;
      float4 w0 = *(const float4*)wp;
      float4 w1 = *(const float4*)(wp + 4);
      float cs = expf(bij[r * 10 + cls] - smx[cls]) * sinv[cls];
      u16 ov[8];
      ov[0] = f2bf(w0.x * cs); ov[1] = f2bf(w0.y * cs);
      ov[2] = f2bf(w0.z * cs); ov[3] = f2bf(w0.w * cs);
      ov[4] = f2bf(w1.x * cs); ov[5] = f2bf(w1.y * cs);
      ov[6] = f2bf(w1.z * cs); ov[7] = f2bf(w1.w * cs);
      *(uint4*)((char*)Asl + row * 144 + qq * 16) = *(uint4*)ov;
    }
#pragma unroll
    for (int j = 0; j < 2; ++j) {  // B: 64 rows x 8 chunks
      int c2 = tid + j * 256;
      int row = c2 >> 3, qq = c2 & 7;
      *(uint4*)((char*)Bsl + row * 144 + qq * 16) =
          *(const uint4*)(ub + (size_t)(n0 + row) * 9216 + kb + qq * 8);
    }
    __syncthreads();
#pragma unroll
    for (int s2 = 0; s2 < 2; ++s2) {
      int xg = (s2 * 4 + fg) * 16;
      short8 bf0 = *(const short8*)((char*)Bsl + (wave * 16 + fr) * 144 + xg);
#pragma unroll
      for (int m = 0; m < 10; ++m) {
        short8 af = *(const short8*)((char*)Asl + (m * 16 + fr) * 144 + xg);
        acc[m] = __builtin_amdgcn_mfma_f32_16x16x32_bf16(af, bf0, acc[m], 0, 0, 0);
      }
    }
  }
  int bcol = n0 + wave * 16 + fr;
#pragma unroll
  for (int m = 0; m < 10; ++m)
#pragma unroll
    for (int qq = 0; qq < 4; ++qq)
      atomicAdd(s + (m * 16 + fg * 4 + qq) * 512 + bcol, acc[m][qq]);
}

// ---------------- squash_v: v = squash(s); re-zeros s for next iteration ----------------
__global__ __launch_bounds__(256) void squash_v_kernel(
    float* __restrict__ s, u16* __restrict__ vb,
    float* __restrict__ outp, int write_out) {
  int idx = blockIdx.x * 256 + threadIdx.x;  // 5120 = c*512 + b
  int c = idx >> 9, b = idx & 511;
  float vals[16];
  float sq = 0.f;
#pragma unroll
  for (int o = 0; o < 16; ++o) {
    float v = s[(c * 16 + o) * 512 + b];
    vals[o] = v;
    sq += v * v;
  }
#pragma unroll
  for (int o = 0; o < 16; ++o) s[(c * 16 + o) * 512 + b] = 0.f;
  float f = sqrtf(sq) / (1.0f + sq);
  if (write_out) {
#pragma unroll
    for (int o = 0; o < 16; ++o) outp[((size_t)b * 10 + c) * 16 + o] = vals[o] * f;
  } else {
#pragma unroll
    for (int o = 0; o < 16; ++o) vb[(c * 16 + o) * 512 + b] = f2bf(vals[o] * f);
  }
}

// ---------------- gemm_gc: G = vb @ ubT^T (in LDS) then bij += W.G/512 ----------------
// grid 288 = 72 nb (128 ri) * 4 kz (128 b each). G_lds pitch 129 f32.
__global__ __launch_bounds__(256) void gemm_gc_kernel(
    const u16* __restrict__ vb, const u16* __restrict__ ubT,
    const float* __restrict__ W, float* __restrict__ bij) {
  __shared__ __align__(16) u16 Agl[160 * 72];
  __shared__ __align__(16) u16 Bgl[128 * 72];
  __shared__ float Gl[160 * 129];
  int nb = blockIdx.x % 72, kzi = blockIdx.x / 72;
  int n0 = nb * 128, k0 = kzi * 128;
  int tid = threadIdx.x;
  int lane = tid & 63, wave = tid >> 6;
  int fr = lane & 15, fg = lane >> 4;
  f32x4 acc[10][2] = {};
#pragma unroll
  for (int st = 0; st < 2; ++st) {
    int kb = k0 + st * 64;
    __syncthreads();
#pragma unroll
    for (int j = 0; j < 5; ++j) {
      int c5 = tid + j * 256;
      int row = c5 >> 3, qq = c5 & 7;
      *(uint4*)((char*)Agl + row * 144 + qq * 16) =
          *(const uint4*)(vb + (size_t)row * 512 + kb + qq * 8);
    }
#pragma unroll
    for (int j = 0; j < 4; ++j) {
      int c4 = tid + j * 256;
      int row = c4 >> 3, qq = c4 & 7;
      *(uint4*)((char*)Bgl + row * 144 + qq * 16) =
          *(const uint4*)(ubT + (size_t)(n0 + row) * 512 + kb + qq * 8);
    }
    __syncthreads();
#pragma unroll
    for (int s2 = 0; s2 < 2; ++s2) {
      int xg = (s2 * 4 + fg) * 16;
      short8 bfv[2];
#pragma unroll
      for (int nn = 0; nn < 2; ++nn)
        bfv[nn] = *(const short8*)((char*)Bgl + (wave * 32 + nn * 16 + fr) * 144 + xg);
#pragma unroll
      for (int m = 0; m < 10; ++m) {
        short8 af = *(const short8*)((char*)Agl + (m * 16 + fr) * 144 + xg);
#pragma unroll
        for (int nn = 0; nn < 2; ++nn)
          acc[m][nn] = __builtin_amdgcn_mfma_f32_16x16x32_bf16(af, bfv[nn],
                                                              acc[m][nn], 0, 0, 0);
      }
    }
  }
  // G -> LDS
#pragma unroll
  for (int m = 0; m < 10; ++m)
#pragma unroll
    for (int nn = 0; nn < 2; ++nn) {
      int col = wave * 32 + nn * 16 + fr;
#pragma unroll
      for (int qq = 0; qq < 4; ++qq)
        Gl[(m * 16 + fg * 4 + qq) * 129 + col] = acc[m][nn][qq];
    }
  __syncthreads();
  // contract: bij[r][c] += (1/512) sum_{o,i} W[r,c,o,i] * G[c*16+o][rl*8+i]
  if (tid < 160) {
    int rl = tid / 10, c = tid - rl * 10;
    int r = (n0 >> 3) + rl;
    const float* wp = W + (size_t)r * 1280 + c * 128;
    float a = 0.f;
#pragma unroll 4
    for (int o = 0; o < 16; ++o) {
      const float* gp = &Gl[(c * 16 + o) * 129 + rl * 8];
#pragma unroll
      for (int i = 0; i < 8; ++i) a = fmaf(wp[o * 8 + i], gp[i], a);
    }
    atomicAdd(&bij[r * 10 + c], a * (1.0f / 512.0f));
  }
}

extern "C" void kernel_launch(void* const* d_in, const int* in_sizes, int n_in,
                              void* d_out, int out_size, void* d_ws, size_t ws_size,
                              hipStream_t stream) {
  const float* x  = (const float*)d_in[0];
  const float* w1 = (const float*)d_in[1];
  const float* b1 = (const float*)d_in[2];
  const float* w2 = (const float*)d_in[3];
  const float* b2 = (const float*)d_in[4];
  const float* W  = (const float*)d_in[5];
  char* ws = (char*)d_ws;
  u16*   hT  = (u16*)ws;
  u16*   A2  = (u16*)(ws + 104857600);
  float* u   = (float*)(ws + 115474432);
  float* bij = (float*)(ws + 134348800);
  float* s   = (float*)(ws + 134440960);
  u16*   ub  = (u16*)ws;                 // aliases dead hT
  u16*   ubT = (u16*)(ws + 9437184);
  u16*   vb  = (u16*)(ws + 21823488);
  float* out = (float*)d_out;

  hipMemsetAsync(bij, 0, 46080, stream);
  hipMemsetAsync(s, 0, 327680, stream);
  init_u_kernel<<<4608, 256, 0, stream>>>(b2, u);
  conv1_kernel<<<dim3(512, 2), 256, 0, stream>>>(x, w1, b1, hT);
  prep_w2_kernel<<<20736, 256, 0, stream>>>(w2, A2);
  conv2_kernel<<<576, 512, 0, stream>>>(hT, A2, u);
  squash_kernel<<<2304, 256, 0, stream>>>(u, ub, ubT);
  for (int it = 0; it < 3; ++it) {
    gemm_s_kernel<<<288, 256, 0, stream>>>(W, bij, ub, s);
    squash_v_kernel<<<20, 256, 0, stream>>>(s, vb, out, it == 2 ? 1 : 0);
    if (it < 2) gemm_gc_kernel<<<288, 256, 0, stream>>>(vb, ubT, W, bij);
  }
}

// Round 6
// 619.231 us; speedup vs baseline: 1.2774x; 1.2774x over previous
//
#include <hip/hip_runtime.h>
#include <stdint.h>

// CapsuleNet forward on MI355X — round 6 (race-fixed 8-phase conv2).
// conv2: BM=BN=256, BK=64, 8 waves, 2 LDS buffers; ALL 8 stage-loads issued
//        at P0 of each tile (target buffer fully dead by then); counted
//        waits: vmcnt(2) @P3-end (A0,B0,B1 of next tile resident by P0),
//        vmcnt(8) @P1-end (A1 of current tile resident by P2), peeled last
//        tile with vmcnt(0). XOR-8 swizzle both sides (128-B rows).
//
// ws layout (total ~134.8 MB):
//   hT  bf16 [512][20][20][256]   @0           104,857,600
//   A2  bf16 [256][20736]         @104,857,600  10,616,832
//   u   f32  [512][9216]          @115,474,432  18,874,368
//   bij f32  [1152][10]           @134,348,800      46,080
//   s   f32  [160][512]           @134,440,960     327,680
//  aliased over dead hT after conv2:
//   ub  bf16 [512][9216]          @0             9,437,184
//   ubT bf16 [9216][512]          @9,437,184     9,437,184
//   vb  bf16 [160][512]           @21,823,488      163,840

typedef unsigned short u16;
typedef unsigned int u32;
typedef short short8 __attribute__((ext_vector_type(8)));
typedef float f32x4 __attribute__((ext_vector_type(4)));

__device__ __forceinline__ u16 f2bf(float f) {
  u32 u = __float_as_uint(f);
  return (u16)((u + 0x7FFFu + ((u >> 16) & 1u)) >> 16);
}

__device__ __forceinline__ void gload_lds16(const void* g, void* l) {
  __builtin_amdgcn_global_load_lds(
      (const __attribute__((address_space(1))) void*)g,
      (__attribute__((address_space(3))) void*)l, 16, 0, 0);
}

// ---------------- conv1 + bias + ReLU -> hT[b][y][x][co] bf16 ----------------
__global__ __launch_bounds__(256) void conv1_kernel(
    const float* __restrict__ x, const float* __restrict__ w1,
    const float* __restrict__ b1, u16* __restrict__ hT) {
  int b = blockIdx.x;
  int co0 = blockIdx.y * 128;
  int t = threadIdx.x;
  if (t >= 200) return;
  int oh = t / 10, ow0 = (t % 10) * 2;
  const float* xb = x + (size_t)b * 784;
  float patch[9][10];
#pragma unroll
  for (int kh = 0; kh < 9; ++kh)
#pragma unroll
    for (int j = 0; j < 10; ++j) patch[kh][j] = xb[(oh + kh) * 28 + ow0 + j];
  u16* hb = hT + ((size_t)b * 400 + oh * 20 + ow0) * 256 + co0;
  for (int c8 = 0; c8 < 16; ++c8) {
    u16 o0[8], o1[8];
#pragma unroll
    for (int cc = 0; cc < 8; ++cc) {
      int co = co0 + c8 * 8 + cc;
      const float* wc = w1 + co * 81;  // block-uniform -> s_load
      float a0 = 0.f, a1 = 0.f;
#pragma unroll
      for (int kh = 0; kh < 9; ++kh)
#pragma unroll
        for (int kw = 0; kw < 9; ++kw) {
          float wv = wc[kh * 9 + kw];
          a0 = fmaf(wv, patch[kh][kw], a0);
          a1 = fmaf(wv, patch[kh][kw + 1], a1);
        }
      float bias = b1[co];
      o0[cc] = f2bf(fmaxf(a0 + bias, 0.f));
      o1[cc] = f2bf(fmaxf(a1 + bias, 0.f));
    }
    *(uint4*)(hb + c8 * 8) = *(uint4*)o0;
    *(uint4*)(hb + 256 + c8 * 8) = *(uint4*)o1;
  }
}

// ---------------- conv2 weights: [co][ci][t] -> bf16 [co][t*256+ci] ----------------
__global__ __launch_bounds__(256) void prep_w2_kernel(
    const float* __restrict__ w2, u16* __restrict__ A2) {
  __shared__ u16 tl[81 * 264];  // pitch 264 u16
  int co = blockIdx.x;
  int tid = threadIdx.x;
  const float* wp = w2 + (size_t)co * 20736;
#pragma unroll
  for (int k = 0; k < 81; ++k) {
    int li = k * 256 + tid;  // li = ci*81 + t
    int ci = li / 81, t = li - ci * 81;
    tl[t * 264 + ci] = f2bf(wp[li]);
  }
  __syncthreads();
  u16* op = A2 + (size_t)co * 20736;
  for (int oc = tid; oc < 2592; oc += 256) {
    int k0 = oc * 8;
    int t = k0 >> 8, ci0 = k0 & 255;
    *(uint4*)(op + k0) = *(const uint4*)&tl[t * 264 + ci0];
  }
}

// ---------------- u := bias (pre-init for conv2 atomic accumulation) ----------------
__global__ __launch_bounds__(256) void init_u_kernel(
    const float* __restrict__ b2, float* __restrict__ u) {
  int i = blockIdx.x * 256 + threadIdx.x;  // 1,179,648 float4s
  int b = i / 2304, j0 = (i - b * 2304) * 4;
  float4 v;
  v.x = b2[j0 / 36]; v.y = b2[(j0 + 1) / 36];
  v.z = b2[(j0 + 2) / 36]; v.w = b2[(j0 + 3) / 36];
  *(float4*)(u + (size_t)b * 9216 + j0) = v;
}

// ---------------- conv2 implicit GEMM: 256x256, BK=64, 8-phase, fixed waits ----------------
// M=256(co) N=18432(b*36+sp) K=324 k-tiles of 64 (tap-major). Grid 216 = 72nb x 3kz.
// LDS 128 KB: [dbuf][A|B][half 128 rows][row 128 B], XOR-8 swizzle:
//   LDS[row][q] = global[row][q ^ (row&7)], read back with same XOR.
__global__ __launch_bounds__(512, 2) void conv2_kernel(
    const u16* __restrict__ hT, const u16* __restrict__ A2,
    float* __restrict__ u) {
  __shared__ __align__(16) u16 lds_[65536];  // 131072 B
  char* const ldsc = (char*)lds_;
  const int bx = blockIdx.x;
  const int nbk = bx % 72, kz = bx / 72;
  const int n0 = nbk * 256;
  const int tid = threadIdx.x;
  const int lane = tid & 63, w = tid >> 6;
  const int wr = w >> 2, wc = w & 3;
  const int fr = lane & 15, fg = lane >> 4;
  const int w1024 = w * 1024;

  // staging: thread covers (row = rA + group*64, chunk qsrc) — 16 B per issue
  const int rA = tid >> 3;
  const int qsrc = (tid & 7) ^ (rA & 7);  // source pre-swizzle (rule 21)
  const int AbaseT = rA * 20736 + qsrc * 8;
  int Bb[4];
#pragma unroll
  for (int rg = 0; rg < 4; ++rg) {
    int n = n0 + rg * 64 + rA;
    int b = n / 36, sp = n - b * 36, oh = sp / 6, ow = sp - oh * 6;
    Bb[rg] = (b * 400 + oh * 40 + ow * 2) * 256 + qsrc * 8;
  }

  // read-side (row&7 == fr&7 for all fragment rows)
  const int kx0 = (fg ^ (fr & 7)) << 4;
  const int kx1 = ((4 + fg) ^ (fr & 7)) << 4;
  const int wr16384 = wr * 16384;
  const int bh16384 = 32768 + (wc >> 1) * 16384;
  const int brow0 = (wc & 1) * 64;

  f32x4 acc[8][4] = {};
  short8 areg[4][2], breg[2][2];

#define STAGE_A(E, H, GT) do {                                               \
    char* p_ = ldsc + (E) * 65536 + (H) * 16384 + w1024;                     \
    gload_lds16(A2 + AbaseT + ((H) * 2 + 0) * 1327104 + (GT) * 64, p_);      \
    gload_lds16(A2 + AbaseT + ((H) * 2 + 1) * 1327104 + (GT) * 64, p_ + 8192); \
  } while (0)
#define STAGE_B(E, H, BOFF) do {                                             \
    char* p_ = ldsc + (E) * 65536 + 32768 + (H) * 16384 + w1024;             \
    gload_lds16(hT + Bb[(H) * 2 + 0] + (BOFF), p_);                          \
    gload_lds16(hT + Bb[(H) * 2 + 1] + (BOFF), p_ + 8192);                   \
  } while (0)
#define STAGE_ALL(E, GT) do {                                                \
    int tap_ = (GT) >> 2;                                                    \
    int kh_ = tap_ / 9, kw_ = tap_ - kh_ * 9;                                \
    int bo_ = (kh_ * 20 + kw_) * 256 + ((GT) & 3) * 64;                      \
    STAGE_A(E, 0, GT); STAGE_B(E, 0, bo_);                                   \
    STAGE_B(E, 1, bo_); STAGE_A(E, 1, GT);                                   \
  } while (0)
#define RD_A(D, MH) do { _Pragma("unroll")                                   \
    for (int mr = 0; mr < 4; ++mr) {                                         \
      const char* r_ = ldsc + (D) * 65536 + wr16384 +                        \
                       ((MH) * 64 + mr * 16 + fr) * 128;                     \
      areg[mr][0] = *(const short8*)(r_ + kx0);                              \
      areg[mr][1] = *(const short8*)(r_ + kx1);                              \
    } } while (0)
#define RD_B(D, NH) do { _Pragma("unroll")                                   \
    for (int nr = 0; nr < 2; ++nr) {                                         \
      const char* r_ = ldsc + (D) * 65536 + bh16384 +                        \
                       (brow0 + (NH) * 32 + nr * 16 + fr) * 128;             \
      breg[nr][0] = *(const short8*)(r_ + kx0);                              \
      breg[nr][1] = *(const short8*)(r_ + kx1);                              \
    } } while (0)
#define MM16(MH, NH) do {                                                    \
    __builtin_amdgcn_s_setprio(1);                                           \
    _Pragma("unroll") for (int mr = 0; mr < 4; ++mr)                         \
    _Pragma("unroll") for (int nr = 0; nr < 2; ++nr) {                       \
      acc[(MH)*4+mr][(NH)*2+nr] = __builtin_amdgcn_mfma_f32_16x16x32_bf16(   \
          areg[mr][0], breg[nr][0], acc[(MH)*4+mr][(NH)*2+nr], 0, 0, 0);     \
      acc[(MH)*4+mr][(NH)*2+nr] = __builtin_amdgcn_mfma_f32_16x16x32_bf16(   \
          areg[mr][1], breg[nr][1], acc[(MH)*4+mr][(NH)*2+nr], 0, 0, 0);     \
    }                                                                        \
    __builtin_amdgcn_s_setprio(0);                                           \
  } while (0)
#define BAR_PRE() do {                                                       \
    __builtin_amdgcn_s_barrier();                                            \
    asm volatile("s_waitcnt lgkmcnt(0)" ::: "memory");                       \
    __builtin_amdgcn_sched_barrier(0);                                       \
  } while (0)
#define BAR_ONLY() do {                                                      \
    __builtin_amdgcn_s_barrier();                                            \
    asm volatile("" ::: "memory");                                           \
  } while (0)
#define VM_BAR(N) do {                                                       \
    asm volatile("s_waitcnt vmcnt(" N ")" ::: "memory");                     \
    __builtin_amdgcn_s_barrier();                                            \
    asm volatile("" ::: "memory");                                           \
  } while (0)
  // Ledger (per thread, 8 loads/tile, all issued at P0, order A0,B0,B1,A1):
  //   end-P3(T): vmcnt(2) -> A0,B0,B1(T+1) landed (issued 4 phases earlier);
  //              only A1(T+1) may remain in flight.
  //   end-P1(T): vmcnt(8) -> the 8 newest are tile T+1's; everything older
  //              (A1(T)) landed before P2 reads it. No stall (5 phases old).
#define TILE_STD(T, D, E) do {                                               \
    RD_A(D, 0); RD_B(D, 0);                                                  \
    STAGE_ALL(E, kz * 108 + (T) + 1);                                        \
    BAR_PRE(); MM16(0, 0); BAR_ONLY();                                       \
    RD_B(D, 1);                                                              \
    BAR_PRE(); MM16(0, 1); VM_BAR("8");                                      \
    RD_A(D, 1);                                                              \
    BAR_PRE(); MM16(1, 1); BAR_ONLY();                                       \
    RD_B(D, 0);                                                              \
    BAR_PRE(); MM16(1, 0); VM_BAR("2");                                      \
  } while (0)
#define TILE_LAST(D) do {                                                    \
    RD_A(D, 0); RD_B(D, 0);                                                  \
    BAR_PRE(); MM16(0, 0); BAR_ONLY();                                       \
    RD_B(D, 1);                                                              \
    BAR_PRE(); MM16(0, 1); VM_BAR("0");                                      \
    RD_A(D, 1);                                                              \
    BAR_PRE(); MM16(1, 1); BAR_ONLY();                                       \
    RD_B(D, 0);                                                              \
    BAR_PRE(); MM16(1, 0);                                                   \
  } while (0)

  // prologue: stage tile 0; A0,B0,B1 must land before P0 -> vmcnt(2)
  STAGE_ALL(0, kz * 108);
  asm volatile("s_waitcnt vmcnt(2)" ::: "memory");
  __builtin_amdgcn_s_barrier();
  asm volatile("" ::: "memory");

  for (int tt = 0; tt < 53; ++tt) {
    TILE_STD(2 * tt, 0, 1);      // tiles 0..104 even
    TILE_STD(2 * tt + 1, 1, 0);  // tiles 1..105 odd
  }
  TILE_STD(106, 0, 1);           // stages tile 107
  TILE_LAST(1);                  // tile 107, no staging

  // epilogue: atomic accumulate into u[b][co*36+sp]
#pragma unroll
  for (int nf = 0; nf < 4; ++nf) {
    int cn = n0 + wc * 64 + nf * 16 + fr;
    int ob = cn / 36;
    int os = cn - ob * 36;
    float* op = u + (size_t)ob * 9216 + os;
#pragma unroll
    for (int mf = 0; mf < 8; ++mf) {
      int row0 = wr * 128 + mf * 16 + fg * 4;
#pragma unroll
      for (int qq = 0; qq < 4; ++qq)
        atomicAdd(op + (row0 + qq) * 36, acc[mf][nf][qq]);
    }
  }
#undef STAGE_A
#undef STAGE_B
#undef STAGE_ALL
#undef RD_A
#undef RD_B
#undef MM16
#undef BAR_PRE
#undef BAR_ONLY
#undef VM_BAR
#undef TILE_STD
#undef TILE_LAST
}

// ---------------- squash u -> ub (b-major) bf16, fully coalesced ----------------
__global__ __launch_bounds__(256) void squash_kernel(
    const float* __restrict__ u, u16* __restrict__ ub) {
  int idx = blockIdx.x * 256 + threadIdx.x;  // 589,824 = b*1152 + r
  const float* up = u + (size_t)idx * 8;
  float4 a = *(const float4*)up;
  float4 c = *(const float4*)(up + 4);
  float sq = a.x * a.x + a.y * a.y + a.z * a.z + a.w * a.w +
             c.x * c.x + c.y * c.y + c.z * c.z + c.w * c.w;
  float f = sqrtf(sq) / (1.0f + sq);
  u16 o[8];
  o[0] = f2bf(a.x * f); o[1] = f2bf(a.y * f);
  o[2] = f2bf(a.z * f); o[3] = f2bf(a.w * f);
  o[4] = f2bf(c.x * f); o[5] = f2bf(c.y * f);
  o[6] = f2bf(c.z * f); o[7] = f2bf(c.w * f);
  *(uint4*)(ub + (size_t)idx * 8) = *(uint4*)o;
}

// ---------------- ubT[ri][b] = ub[b][ri] via LDS tile transpose ----------------
__global__ __launch_bounds__(256) void transp_kernel(
    const u16* __restrict__ ub, u16* __restrict__ ubT) {
  __shared__ u16 tl[64][72];
  int ri0 = blockIdx.x * 64, b0 = blockIdx.y * 64;
  int tid = threadIdx.x;
  int br = tid >> 2, cq = tid & 3;
  const u16* ip = ub + (size_t)(b0 + br) * 9216 + ri0 + cq * 16;
  uint4 v0 = *(const uint4*)ip;
  uint4 v1 = *(const uint4*)(ip + 8);
  *(uint4*)&tl[br][cq * 16] = v0;
  *(uint4*)&tl[br][cq * 16 + 8] = v1;
  __syncthreads();
  int rr = tid >> 2, cb = tid & 3;
  u16 o0[8], o1[8];
#pragma unroll
  for (int j = 0; j < 8; ++j) {
    o0[j] = tl[cb * 16 + j][rr];
    o1[j] = tl[cb * 16 + 8 + j][rr];
  }
  u16* opp = ubT + (size_t)(ri0 + rr) * 512 + b0 + cb * 16;
  *(uint4*)opp = *(uint4*)o0;
  *(uint4*)(opp + 8) = *(uint4*)o1;
}

// ---------------- gemm_s (softmax fused): s[160co][512b] += softmax(bij)*W @ ub^T ----------------
__global__ __launch_bounds__(256) void gemm_s_kernel(
    const float* __restrict__ W, const float* __restrict__ bij,
    const u16* __restrict__ ub, float* __restrict__ s) {
  __shared__ __align__(16) u16 Asl[160 * 72];
  __shared__ __align__(16) u16 Bsl[64 * 72];
  __shared__ float smx[10], sinv[10];
  int nb = blockIdx.x & 7, kzi = blockIdx.x >> 3;
  int n0 = nb * 64, k0 = kzi * 256;
  int tid = threadIdx.x;
  int lane = tid & 63, wave = tid >> 6;
  int fr = lane & 15, fg = lane >> 4;

  for (int c = wave; c < 10; c += 4) {
    float mx = -1e30f;
    for (int r = lane; r < 1152; r += 64) mx = fmaxf(mx, bij[r * 10 + c]);
#pragma unroll
    for (int d = 1; d < 64; d <<= 1) mx = fmaxf(mx, __shfl_xor(mx, d, 64));
    float sm = 0.f;
    for (int r = lane; r < 1152; r += 64) sm += expf(bij[r * 10 + c] - mx);
#pragma unroll
    for (int d = 1; d < 64; d <<= 1) sm += __shfl_xor(sm, d, 64);
    if (lane == 0) { smx[c] = mx; sinv[c] = 1.0f / sm; }
  }

  f32x4 acc[10] = {};
#pragma unroll
  for (int st = 0; st < 4; ++st) {
    int kb = k0 + st * 64;
    __syncthreads();
#pragma unroll
    for (int j = 0; j < 5; ++j) {
      int c5 = tid + j * 256;
      int row = c5 >> 3, qq = c5 & 7;
      int cls = row >> 4, o = row & 15;
      int r = (kb + qq * 8) >> 3;
      const float* wp = W + (size_t)r * 1280 + cls * 128 + o * 8;
      float4 w0 = *(const float4*)wp;
      float4 w1 = *(const float4*)(wp + 4);
      float cs = expf(bij[r * 10 + cls] - smx[cls]) * sinv[cls];
      u16 ov[8];
      ov[0] = f2bf(w0.x * cs); ov[1] = f2bf(w0.y * cs);
      ov[2] = f2bf(w0.z * cs); ov[3] = f2bf(w0.w * cs);
      ov[4] = f2bf(w1.x * cs); ov[5] = f2bf(w1.y * cs);
      ov[6] = f2bf(w1.z * cs); ov[7] = f2bf(w1.w * cs);
      *(uint4*)((char*)Asl + row * 144 + qq * 16) = *(uint4*)ov;
    }
#pragma unroll
    for (int j = 0; j < 2; ++j) {
      int c2 = tid + j * 256;
      int row = c2 >> 3, qq = c2 & 7;
      *(uint4*)((char*)Bsl + row * 144 + qq * 16) =
          *(const uint4*)(ub + (size_t)(n0 + row) * 9216 + kb + qq * 8);
    }
    __syncthreads();
#pragma unroll
    for (int s2 = 0; s2 < 2; ++s2) {
      int xg = (s2 * 4 + fg) * 16;
      short8 bf0 = *(const short8*)((char*)Bsl + (wave * 16 + fr) * 144 + xg);
#pragma unroll
      for (int m = 0; m < 10; ++m) {
        short8 af = *(const short8*)((char*)Asl + (m * 16 + fr) * 144 + xg);
        acc[m] = __builtin_amdgcn_mfma_f32_16x16x32_bf16(af, bf0, acc[m], 0, 0, 0);
      }
    }
  }
  int bcol = n0 + wave * 16 + fr;
#pragma unroll
  for (int m = 0; m < 10; ++m)
#pragma unroll
    for (int qq = 0; qq < 4; ++qq)
      atomicAdd(s + (m * 16 + fg * 4 + qq) * 512 + bcol, acc[m][qq]);
}

// ---------------- squash_v: v = squash(s); re-zeros s ----------------
__global__ __launch_bounds__(256) void squash_v_kernel(
    float* __restrict__ s, u16* __restrict__ vb,
    float* __restrict__ outp, int write_out) {
  int idx = blockIdx.x * 256 + threadIdx.x;  // 5120 = c*512 + b
  int c = idx >> 9, b = idx & 511;
  float vals[16];
  float sq = 0.f;
#pragma unroll
  for (int o = 0; o < 16; ++o) {
    float v = s[(c * 16 + o) * 512 + b];
    vals[o] = v;
    sq += v * v;
  }
#pragma unroll
  for (int o = 0; o < 16; ++o) s[(c * 16 + o) * 512 + b] = 0.f;
  float f = sqrtf(sq) / (1.0f + sq);
  if (write_out) {
#pragma unroll
    for (int o = 0; o < 16; ++o) outp[((size_t)b * 10 + c) * 16 + o] = vals[o] * f;
  } else {
#pragma unroll
    for (int o = 0; o < 16; ++o) vb[(c * 16 + o) * 512 + b] = f2bf(vals[o] * f);
  }
}

// ---------------- gemm_gc: G = vb @ ubT^T (LDS) then bij += W.G/512 ----------------
__global__ __launch_bounds__(256) void gemm_gc_kernel(
    const u16* __restrict__ vb, const u16* __restrict__ ubT,
    const float* __restrict__ W, float* __restrict__ bij) {
  __shared__ __align__(16) u16 Agl[160 * 72];
  __shared__ __align__(16) u16 Bgl[128 * 72];
  __shared__ float Gl[160 * 129];
  int nb = blockIdx.x % 72, kzi = blockIdx.x / 72;
  int n0 = nb * 128, k0 = kzi * 128;
  int tid = threadIdx.x;
  int lane = tid & 63, wave = tid >> 6;
  int fr = lane & 15, fg = lane >> 4;
  f32x4 acc[10][2] = {};
#pragma unroll
  for (int st = 0; st < 2; ++st) {
    int kb = k0 + st * 64;
    __syncthreads();
#pragma unroll
    for (int j = 0; j < 5; ++j) {
      int c5 = tid + j * 256;
      int row = c5 >> 3, qq = c5 & 7;
      *(uint4*)((char*)Agl + row * 144 + qq * 16) =
          *(const uint4*)(vb + (size_t)row * 512 + kb + qq * 8);
    }
#pragma unroll
    for (int j = 0; j < 4; ++j) {
      int c4 = tid + j * 256;
      int row = c4 >> 3, qq = c4 & 7;
      *(uint4*)((char*)Bgl + row * 144 + qq * 16) =
          *(const uint4*)(ubT + (size_t)(n0 + row) * 512 + kb + qq * 8);
    }
    __syncthreads();
#pragma unroll
    for (int s2 = 0; s2 < 2; ++s2) {
      int xg = (s2 * 4 + fg) * 16;
      short8 bfv[2];
#pragma unroll
      for (int nn = 0; nn < 2; ++nn)
        bfv[nn] = *(const short8*)((char*)Bgl + (wave * 32 + nn * 16 + fr) * 144 + xg);
#pragma unroll
      for (int m = 0; m < 10; ++m) {
        short8 af = *(const short8*)((char*)Agl + (m * 16 + fr) * 144 + xg);
#pragma unroll
        for (int nn = 0; nn < 2; ++nn)
          acc[m][nn] = __builtin_amdgcn_mfma_f32_16x16x32_bf16(af, bfv[nn],
                                                              acc[m][nn], 0, 0, 0);
      }
    }
  }
#pragma unroll
  for (int m = 0; m < 10; ++m)
#pragma unroll
    for (int nn = 0; nn < 2; ++nn) {
      int col = wave * 32 + nn * 16 + fr;
#pragma unroll
      for (int qq = 0; qq < 4; ++qq)
        Gl[(m * 16 + fg * 4 + qq) * 129 + col] = acc[m][nn][qq];
    }
  __syncthreads();
  if (tid < 160) {
    int rl = tid / 10, c = tid - rl * 10;
    int r = (n0 >> 3) + rl;
    const float* wp = W + (size_t)r * 1280 + c * 128;
    float a = 0.f;
#pragma unroll 4
    for (int o = 0; o < 16; ++o) {
      const float* gp = &Gl[(c * 16 + o) * 129 + rl * 8];
#pragma unroll
      for (int i = 0; i < 8; ++i) a = fmaf(wp[o * 8 + i], gp[i], a);
    }
    atomicAdd(&bij[r * 10 + c], a * (1.0f / 512.0f));
  }
}

extern "C" void kernel_launch(void* const* d_in, const int* in_sizes, int n_in,
                              void* d_out, int out_size, void* d_ws, size_t ws_size,
                              hipStream_t stream) {
  const float* x  = (const float*)d_in[0];
  const float* w1 = (const float*)d_in[1];
  const float* b1 = (const float*)d_in[2];
  const float* w2 = (const float*)d_in[3];
  const float* b2 = (const float*)d_in[4];
  const float* W  = (const float*)d_in[5];
  char* ws = (char*)d_ws;
  u16*   hT  = (u16*)ws;
  u16*   A2  = (u16*)(ws + 104857600);
  float* u   = (float*)(ws + 115474432);
  float* bij = (float*)(ws + 134348800);
  float* s   = (float*)(ws + 134440960);
  u16*   ub  = (u16*)ws;                 // aliases dead hT
  u16*   ubT = (u16*)(ws + 9437184);
  u16*   vb  = (u16*)(ws + 21823488);
  float* out = (float*)d_out;

  hipMemsetAsync(bij, 0, 46080, stream);
  hipMemsetAsync(s, 0, 327680, stream);
  init_u_kernel<<<4608, 256, 0, stream>>>(b2, u);
  conv1_kernel<<<dim3(512, 2), 256, 0, stream>>>(x, w1, b1, hT);
  prep_w2_kernel<<<256, 256, 0, stream>>>(w2, A2);
  conv2_kernel<<<216, 512, 0, stream>>>(hT, A2, u);
  squash_kernel<<<2304, 256, 0, stream>>>(u, ub);
  transp_kernel<<<dim3(144, 8), 256, 0, stream>>>(ub, ubT);
  for (int it = 0; it < 3; ++it) {
    gemm_s_kernel<<<288, 256, 0, stream>>>(W, bij, ub, s);
    squash_v_kernel<<<20, 256, 0, stream>>>(s, vb, out, it == 2 ? 1 : 0);
    if (it < 2) gemm_gc_kernel<<<288, 256, 0, stream>>>(vb, ubT, W, bij);
  }
}